// Round 13
// baseline (679.927 us; speedup 1.0000x reference)
//
#include <hip/hip_runtime.h>
#include <hip/hip_bf16.h>
#include <math.h>

#define H_ 512
#define VN_ 1000
#define NG_ 10003    // VT+3
#define NGP_ 10240   // padded N (80 tiles of 128)
#define NCHUNK 80
#define A_ 50
#define B_ 8
#define L_ 128
#define R_ 1024      // L*B

typedef __hip_bfloat16 bf16;
typedef __attribute__((ext_vector_type(8))) short bf16x8;
typedef __attribute__((ext_vector_type(4))) float f32x4;

typedef union { unsigned long long u[2]; bf16x8 v; } frag_u;

__device__ __forceinline__ float fsig(float x) { return 1.0f / (1.0f + __expf(-x)); }
__device__ __forceinline__ float ftanh(float x) { return 1.0f - 2.0f / (1.0f + __expf(2.0f * x)); }

__device__ __forceinline__ short b16(float v) {
    __hip_bfloat16 h = __float2bfloat16(v);
    return *(short*)&h;
}

__device__ __forceinline__ unsigned long long ald(const unsigned long long* p) {
    return __hip_atomic_load(p, __ATOMIC_RELAXED, __HIP_MEMORY_SCOPE_AGENT);
}
__device__ __forceinline__ int aldi(const int* p) {
    return __hip_atomic_load(p, __ATOMIC_RELAXED, __HIP_MEMORY_SCOPE_AGENT);
}
__device__ __forceinline__ void ast32(unsigned int* p, unsigned int v) {
    __hip_atomic_store(p, v, __ATOMIC_RELAXED, __HIP_MEMORY_SCOPE_AGENT);
}
__device__ __forceinline__ void asti(int* p, int v) {
    __hip_atomic_store(p, v, __ATOMIC_RELAXED, __HIP_MEMORY_SCOPE_AGENT);
}

// ---------------- prep: flags + bias concat + out init + W_ih->bf16 + embedding ----------------
__global__ void k_prep(int* flags, float* bkq,
                       const float* __restrict__ bmem, const float* __restrict__ bhid,
                       float* out,
                       const float* __restrict__ Wih, bf16* __restrict__ wihb,
                       const int* __restrict__ nt, const int* __restrict__ tt,
                       const float* __restrict__ embN, const float* __restrict__ embT,
                       bf16* __restrict__ X)
{
    const int i = blockIdx.x * 256 + threadIdx.x;   // 0 .. 524287
    const int total = gridDim.x * 256;
    if (i < 32)
        __hip_atomic_store(&flags[i], 0, __ATOMIC_RELAXED, __HIP_MEMORY_SCOPE_AGENT);
    if (i < 1024) bkq[i] = (i < 512) ? bmem[i] : bhid[i - 512];
    if (i == 0) out[0] = 0.f;
    for (int j = i; j < 2048 * 512; j += total)
        wihb[j] = __float2bfloat16(Wih[j]);
    {
        int r = i >> 9, k = i & 511;
        int t = r >> 3, b = r & 7;
        float v;
        if (k < 256) {
            int id = (t == 0) ? 0 : nt[b * L_ + t - 1];
            v = embN[id * 256 + k];
        } else {
            int id = (t == 0) ? 0 : tt[b * L_ + t - 1];
            v = embT[id * 256 + (k - 256)];
        }
        X[i] = __float2bfloat16(v);
    }
}

// ---------------- persistent LSTM (8 blocks x 512 thr) + side work (blocks 8+) ----------------
#define LSTM_BLOCKS 8
#define XTRA 248

#define DECLW(i) bf16x8 Wa##i, Wb##i;
#define LOADW(i) { \
    float4 a0 = *(const float4*)(wr0 + (i)*32); \
    float4 a1 = *(const float4*)(wr0 + (i)*32 + 4); \
    float4 c0 = *(const float4*)(wr1 + (i)*32); \
    float4 c1 = *(const float4*)(wr1 + (i)*32 + 4); \
    Wa##i[0]=b16(a0.x); Wa##i[1]=b16(a0.y); Wa##i[2]=b16(a0.z); Wa##i[3]=b16(a0.w); \
    Wa##i[4]=b16(a1.x); Wa##i[5]=b16(a1.y); Wa##i[6]=b16(a1.z); Wa##i[7]=b16(a1.w); \
    Wb##i[0]=b16(c0.x); Wb##i[1]=b16(c0.y); Wb##i[2]=b16(c0.z); Wb##i[3]=b16(c0.w); \
    Wb##i[4]=b16(c1.x); Wb##i[5]=b16(c1.y); Wb##i[6]=b16(c1.z); Wb##i[7]=b16(c1.w); }
#define LDF(i) frag_u fu##i; fu##i.u[0] = ald(src + (i)*128); fu##i.u[1] = ald(src + (i)*128 + 1);
#define MM(i) \
    acc0 = __builtin_amdgcn_mfma_f32_16x16x32_bf16(Wa##i, fu##i.v, acc0, 0, 0, 0); \
    acc1 = __builtin_amdgcn_mfma_f32_16x16x32_bf16(Wb##i, fu##i.v, acc1, 0, 0, 0);

__launch_bounds__(512, 1)
__global__ void k_lstm(const float* __restrict__ Whh, const float* __restrict__ xg,
                       bf16* __restrict__ hsb,
                       unsigned long long* __restrict__ bfr, int* __restrict__ flags,
                       const float* __restrict__ Wg, bf16* __restrict__ WT,
                       const float* __restrict__ Wmem, const float* __restrict__ Whid,
                       bf16* __restrict__ wkq)
{
    __shared__ float gl[4][64][9];   // [gate][unit][batch] (+pad)  -- LSTM path
    __shared__ short S[64][65];      // transpose staging           -- extra-block path
    const int tid  = threadIdx.x;
    const int x    = blockIdx.x;

    if (x >= LSTM_BLOCKS) {
        // ---- side work riding under the latency-bound LSTM (no polling!) ----
        const int d = x - LSTM_BLOCKS;
        for (int i = d * 512 + tid; i < 2 * 512 * 512; i += XTRA * 512) {
            float v = (i < 512 * 512) ? Wmem[i] : Whid[i - 512 * 512];
            wkq[i] = __float2bfloat16(v);
        }
        const int c = tid & 63;
        const int r0 = (tid >> 6) * 8;       // 8 waves x 8 rows = 64 rows
        const int n_l = tid >> 3;            // 0..63
        const int kq = (tid & 7) * 8;        // 8 chunks of 8
        for (int tile = d; tile < 160 * 24; tile += XTRA) {
            int n0 = (tile % 160) * 64, k0 = (tile / 160) * 64;
            __syncthreads();
            #pragma unroll
            for (int i = 0; i < 8; ++i) {
                int k = r0 + i;
                int n = n0 + c;
                float v = (n < NG_) ? Wg[(size_t)(k0 + k) * NG_ + n] : 0.f;
                S[c][k] = b16(v);
            }
            __syncthreads();
            bf16x8 v;
            #pragma unroll
            for (int e = 0; e < 8; ++e) v[e] = S[n_l][kq + e];
            *(bf16x8*)(WT + (size_t)(n0 + n_l) * 1536 + k0 + kq) = v;
        }
        return;
    }

    const int lane = tid & 63;
    const int wv   = tid >> 6;       // wave 0..7
    const int g    = wv >> 1;        // gate index 0..3 (i,f,g,o)
    const int hh   = wv & 1;         // unit-half within block
    const int m_l  = lane & 15;      // MFMA row within tile
    const int kg   = lane >> 4;      // k-group
    const int n    = lane & 15;      // MFMA col = batch (valid < 8)
    unsigned int* bfr32 = (unsigned int*)bfr;

    // ---- Whh rows -> VGPR/AGPR bf16 A-fragments (once) ----
    const float* wr0 = Whh + (size_t)(g * 512 + x * 64 + hh * 32 + m_l) * 512 + kg * 8;
    const float* wr1 = wr0 + (size_t)16 * 512;
    DECLW(0)  DECLW(1)  DECLW(2)  DECLW(3)  DECLW(4)  DECLW(5)  DECLW(6)  DECLW(7)
    DECLW(8)  DECLW(9)  DECLW(10) DECLW(11) DECLW(12) DECLW(13) DECLW(14) DECLW(15)
    LOADW(0)  LOADW(1)  LOADW(2)  LOADW(3)  LOADW(4)  LOADW(5)  LOADW(6)  LOADW(7)
    LOADW(8)  LOADW(9)  LOADW(10) LOADW(11) LOADW(12) LOADW(13) LOADW(14) LOADW(15)
    asm volatile("" : "+v"(Wa0), "+v"(Wb0), "+v"(Wa1), "+v"(Wb1), "+v"(Wa2), "+v"(Wb2),
                      "+v"(Wa3), "+v"(Wb3), "+v"(Wa4), "+v"(Wb4), "+v"(Wa5), "+v"(Wb5),
                      "+v"(Wa6), "+v"(Wb6), "+v"(Wa7), "+v"(Wb7));
    asm volatile("" : "+v"(Wa8), "+v"(Wb8), "+v"(Wa9), "+v"(Wb9), "+v"(Wa10), "+v"(Wb10),
                      "+v"(Wa11), "+v"(Wb11), "+v"(Wa12), "+v"(Wb12), "+v"(Wa13), "+v"(Wb13),
                      "+v"(Wa14), "+v"(Wb14), "+v"(Wa15), "+v"(Wb15));

    const int u_l = tid >> 3;        // pointwise: unit 0..63
    const int b   = tid & 7;         //            batch 0..7
    const int kt  = 2 * x + (u_l >> 5);  // producer k-tile
    const int uu  = u_l & 31;            // unit within k-tile
    float creg = 0.f;
    int fearly = 0;                  // pre-sampled flag value (monotone -> safe)

    for (int t = 0; t < L_; ++t) {
        const float* xr = xg + ((size_t)t * B_ + b) * 2048 + x * 64 + u_l;
        float xi = xr[0], xf = xr[512], xgg = xr[1024], xo = xr[1536];

        f32x4 acc0 = {0.f, 0.f, 0.f, 0.f};
        f32x4 acc1 = {0.f, 0.f, 0.f, 0.f};
        if (t > 0) {
            if (!__all(fearly >= t)) {
                for (;;) {
                    int v = (lane < LSTM_BLOCKS) ? aldi(&flags[lane]) : t;
                    if (__all(v >= t)) break;
                    __builtin_amdgcn_s_sleep(1);
                }
            }
            const unsigned long long* src =
                bfr + (size_t)((t + 1) & 1) * 2048 + lane * 2;
            LDF(0)  LDF(1)  LDF(2)  LDF(3)  LDF(4)  LDF(5)  LDF(6)  LDF(7)
            LDF(8)  LDF(9)  LDF(10) LDF(11) LDF(12) LDF(13) LDF(14) LDF(15)
            __builtin_amdgcn_sched_barrier(0);
            MM(0)  MM(1)  MM(2)  MM(3)  MM(4)  MM(5)  MM(6)  MM(7)
            MM(8)  MM(9)  MM(10) MM(11) MM(12) MM(13) MM(14) MM(15)
        }
        // D layout: col = lane&15 (batch), row = kg*4 + i (unit within 16-tile)
        if (n < 8) {
            #pragma unroll
            for (int i = 0; i < 4; ++i) {
                gl[g][hh * 32 + kg * 4 + i][n]      = acc0[i];
                gl[g][hh * 32 + 16 + kg * 4 + i][n] = acc1[i];
            }
        }
        __syncthreads();
        // pointwise LSTM cell: thread = (unit u_l, batch b), exactly 512 threads
        float gi = gl[0][u_l][b] + xi;
        float gf = gl[1][u_l][b] + xf;
        float gg = gl[2][u_l][b] + xgg;
        float go = gl[3][u_l][b] + xo;
        float iv = fsig(gi), fv = fsig(gf), gv = ftanh(gg), ov = fsig(go);
        creg = fv * creg + iv * gv;
        float h = ov * ftanh(creg);
        float h2 = __shfl_xor(h, 8);   // partner unit u_l^1 (same wave)
        unsigned pay = 0;
        if ((u_l & 1) == 0) {
            pay = (unsigned)(unsigned short)b16(h)
                | ((unsigned)(unsigned short)b16(h2) << 16);
            int q = uu >> 3, p = (uu & 7) >> 1;
            ast32(bfr32 + (size_t)(t & 1) * 4096 + kt * 256 + (b + 16 * q) * 4 + p, pay);
        }
        fearly = (lane < LSTM_BLOCKS && lane != x) ? aldi(&flags[lane]) : 0x7FFFFFFF;
        asm volatile("s_waitcnt vmcnt(0)" ::: "memory");  // frag stores (and sample) done
        __syncthreads();
        if (tid == 0)
            asti(&flags[x], t + 1);
        if ((u_l & 1) == 0)
            *(unsigned int*)(hsb + (size_t)(t * B_ + b) * 512 + x * 64 + u_l) = pay;
    }
}

// ---------------- attention + context + gcat(bf16) + st, one block per (t,b) ----------------
__launch_bounds__(256)
__global__ void k_attn(const bf16* __restrict__ hsb, const float* __restrict__ kmq,
                       const float* __restrict__ vw,
                       const float* __restrict__ vb, const int* __restrict__ nt,
                       const int* __restrict__ pt, const float* __restrict__ Wsv,
                       const float* __restrict__ bs, bf16* __restrict__ gcat,
                       float* __restrict__ logattn, float* __restrict__ stbuf)
{
    const int r = blockIdx.x;
    const int t = r >> 3, b = r & 7;
    const int tid = threadIdx.x;
    const int lane = tid & 63, wave = tid >> 6;
    int s = t - A_; if (s < 0) s = 0;
    __shared__ float qv[512];
    __shared__ float vwl[512];
    __shared__ float sc[A_];
    __shared__ float attn[A_];
    __shared__ float red[4];
    for (int i = tid; i < 512; i += 256) {
        qv[i] = kmq[(size_t)r * 1024 + 512 + i];   // QB half
        vwl[i] = vw[i];
    }
    __syncthreads();
    for (int a = wave; a < A_; a += 4) {
        int pos = s + a;
        float v = -1e20f;
        bool masked = (pos >= t) || (nt[b * L_ + pos] == VN_ - 1);
        if (!masked) {
            const float* kr = kmq + (size_t)(pos * B_ + b) * 1024;   // KM half
            float p = 0.f;
            for (int k = lane; k < 512; k += 64)
                p += vwl[k] * ftanh(qv[k] + kr[k]);
            for (int off = 32; off; off >>= 1) p += __shfl_down(p, off);
            v = p + vb[0];
        }
        if (lane == 0) sc[a] = v;
    }
    __syncthreads();
    if (tid < 64) {   // masked softmax over 50 (exact -1e20 semantics; all-masked -> uniform)
        float v = (tid < A_) ? sc[tid] : -INFINITY;
        float m = v;
        for (int off = 32; off; off >>= 1) m = fmaxf(m, __shfl_xor(m, off));
        float e = (tid < A_) ? expf(v - m) : 0.f;
        float d = e;
        for (int off = 32; off; off >>= 1) d += __shfl_xor(d, off);
        if (tid < A_) {
            attn[tid] = e / d;
            logattn[(size_t)r * A_ + tid] = (v - m) - logf(d);
        }
    }
    __syncthreads();
    const int k0 = tid * 2;
    float c0 = 0.f, c1 = 0.f;
    for (int a = 0; a < A_; ++a) {
        int pos = s + a;
        if (pos >= t) break;   // hs rows >= t were zeros at step t (ref semantics)
        float w = attn[a];
        unsigned u = *(const unsigned*)((const unsigned short*)hsb + (size_t)(pos * B_ + b) * 512 + k0);
        c0 += w * __uint_as_float(u << 16);
        c1 += w * __uint_as_float(u & 0xffff0000u);
    }
    unsigned ucur = *(const unsigned*)((const unsigned short*)hsb + (size_t)(t * B_ + b) * 512 + k0);
    int par = (t == 0) ? 0 : pt[b * L_ + t - 1];
    unsigned upar = 0;
    if (par < t)
        upar = *(const unsigned*)((const unsigned short*)hsb + (size_t)(par * B_ + b) * 512 + k0);
    float hx = __uint_as_float(ucur << 16), hy = __uint_as_float(ucur & 0xffff0000u);
    bf16* g = gcat + (size_t)r * 1536;
    g[k0]     = __float2bfloat16(c0);
    g[k0 + 1] = __float2bfloat16(c1);
    *(unsigned*)(g + 512 + k0)  = ucur;
    *(unsigned*)(g + 1024 + k0) = upar;
    float part = c0 * Wsv[k0] + c1 * Wsv[k0 + 1]
               + hx * Wsv[512 + k0] + hy * Wsv[512 + k0 + 1];
    for (int off = 32; off; off >>= 1) part += __shfl_down(part, off);
    if (lane == 0) red[wave] = part;
    __syncthreads();
    if (tid == 0) {
        float z = red[0] + red[1] + red[2] + red[3] + bs[0];
        stbuf[r] = -log1pf(expf(-z));   // log_sigmoid(z)
    }
}

// ---------------- 128x128 MFMA GEMM with global_load_lds + bias: XG / KMQ ----------------
__launch_bounds__(256, 2)
__global__ void k_gemm128b(const bf16* __restrict__ Ag, const bf16* __restrict__ Bg,
                           const float* __restrict__ b1, const float* __restrict__ b2,
                           float* __restrict__ C, int N, int K)
{
    __shared__ short As[128 * 32];
    __shared__ short Bs[128 * 32];
    const int tid = threadIdx.x;
    const int lane = tid & 63, wave = tid >> 6;
    const int wr = wave >> 1, wc = wave & 1;
    const int m0 = blockIdx.y * 128, n0 = blockIdx.x * 128;
    f32x4 acc[4][4] = {};
    for (int k0 = 0; k0 < K; k0 += 32) {
        __syncthreads();
        #pragma unroll
        for (int h = 0; h < 2; ++h) {
            int o = tid + h * 256;
            int row = o >> 2;
            int kc = (o & 3) ^ (row & 3);
            const bf16* ga = Ag + (size_t)(m0 + row) * K + k0 + kc * 8;
            const bf16* gb = Bg + (size_t)(n0 + row) * K + k0 + kc * 8;
            unsigned ldso = h * 4096 + wave * 1024;
            __builtin_amdgcn_global_load_lds(
                (const __attribute__((address_space(1))) void*)ga,
                (__attribute__((address_space(3))) void*)((char*)As + ldso), 16, 0, 0);
            __builtin_amdgcn_global_load_lds(
                (const __attribute__((address_space(1))) void*)gb,
                (__attribute__((address_space(3))) void*)((char*)Bs + ldso), 16, 0, 0);
        }
        asm volatile("s_waitcnt vmcnt(0)" ::: "memory");
        __syncthreads();
        bf16x8 af[4], bf[4];
        #pragma unroll
        for (int mi = 0; mi < 4; ++mi) {
            int ra = wr * 64 + mi * 16 + (lane & 15);
            af[mi] = *(const bf16x8*)&As[ra * 32 + (((lane >> 4) ^ (ra & 3)) * 8)];
        }
        #pragma unroll
        for (int ni = 0; ni < 4; ++ni) {
            int rb = wc * 64 + ni * 16 + (lane & 15);
            bf[ni] = *(const bf16x8*)&Bs[rb * 32 + (((lane >> 4) ^ (rb & 3)) * 8)];
        }
        #pragma unroll
        for (int mi = 0; mi < 4; ++mi)
            #pragma unroll
            for (int ni = 0; ni < 4; ++ni)
                acc[mi][ni] = __builtin_amdgcn_mfma_f32_16x16x32_bf16(af[mi], bf[ni], acc[mi][ni], 0, 0, 0);
    }
    const int col = lane & 15, rq = (lane >> 4) * 4;
    #pragma unroll
    for (int mi = 0; mi < 4; ++mi)
        #pragma unroll
        for (int ni = 0; ni < 4; ++ni) {
            int nn = n0 + wc * 64 + ni * 16 + col;
            float bias = (b1 ? b1[nn] : 0.f) + (b2 ? b2[nn] : 0.f);
            #pragma unroll
            for (int i = 0; i < 4; ++i)
                C[(size_t)(m0 + wr * 64 + mi * 16 + rq + i) * N + nn] = acc[mi][ni][i] + bias;
        }
}

// ---------------- fused logits GEMM (128x128/block) + online LSE/argmax partials ----------------
__launch_bounds__(256, 2)
__global__ void k_gemm128p(const bf16* __restrict__ Ag, const bf16* __restrict__ Bg,
                           const float* __restrict__ bg, const int* __restrict__ tt,
                           float* __restrict__ pst)
{
    __shared__ short As[128 * 32];
    __shared__ short Bs[128 * 32];
    __shared__ float bgl[128];
    __shared__ float mrg[128][6];
    const int tid = threadIdx.x;
    const int lane = tid & 63, wave = tid >> 6;
    const int wr = wave >> 1, wc = wave & 1;
    const int col16 = lane & 15, rq = (lane >> 4) * 4;
    const int chunk = blockIdx.x;
    const int m0 = blockIdx.y * 128;
    const int n0 = chunk * 128;
    const int K = 1536;

    if (tid < 128) bgl[tid] = (n0 + tid < NG_) ? bg[n0 + tid] : -INFINITY;

    float M[4][4], S[4][4], AV[4][4], TGT[4][4]; int AI[4][4]; int tgt[4][4];
    #pragma unroll
    for (int mi = 0; mi < 4; ++mi)
        #pragma unroll
        for (int i = 0; i < 4; ++i) {
            M[mi][i] = -INFINITY; S[mi][i] = 0.f; AV[mi][i] = -INFINITY;
            TGT[mi][i] = -INFINITY; AI[mi][i] = 0x7FFFFFFF;
            int row = m0 + wr * 64 + mi * 16 + rq + i;
            tgt[mi][i] = tt[(row & 7) * L_ + (row >> 3)];
        }

    f32x4 acc[4][4] = {};
    for (int k0 = 0; k0 < K; k0 += 32) {
        __syncthreads();
        #pragma unroll
        for (int h = 0; h < 2; ++h) {
            int o = tid + h * 256;
            int row = o >> 2;
            int kc = (o & 3) ^ (row & 3);
            const bf16* ga = Ag + (size_t)(m0 + row) * K + k0 + kc * 8;
            const bf16* gb = Bg + (size_t)(n0 + row) * K + k0 + kc * 8;
            unsigned ldso = h * 4096 + wave * 1024;
            __builtin_amdgcn_global_load_lds(
                (const __attribute__((address_space(1))) void*)ga,
                (__attribute__((address_space(3))) void*)((char*)As + ldso), 16, 0, 0);
            __builtin_amdgcn_global_load_lds(
                (const __attribute__((address_space(1))) void*)gb,
                (__attribute__((address_space(3))) void*)((char*)Bs + ldso), 16, 0, 0);
        }
        asm volatile("s_waitcnt vmcnt(0)" ::: "memory");
        __syncthreads();
        bf16x8 af[4], bf[4];
        #pragma unroll
        for (int mi = 0; mi < 4; ++mi) {
            int ra = wr * 64 + mi * 16 + col16;
            af[mi] = *(const bf16x8*)&As[ra * 32 + (((lane >> 4) ^ (ra & 3)) * 8)];
        }
        #pragma unroll
        for (int ni = 0; ni < 4; ++ni) {
            int rb = wc * 64 + ni * 16 + col16;
            bf[ni] = *(const bf16x8*)&Bs[rb * 32 + (((lane >> 4) ^ (rb & 3)) * 8)];
        }
        #pragma unroll
        for (int mi = 0; mi < 4; ++mi)
            #pragma unroll
            for (int ni = 0; ni < 4; ++ni)
                acc[mi][ni] = __builtin_amdgcn_mfma_f32_16x16x32_bf16(af[mi], bf[ni], acc[mi][ni], 0, 0, 0);
    }
    // ---- per-row stats over this 128-col tile ----
    #pragma unroll
    for (int mi = 0; mi < 4; ++mi)
        #pragma unroll
        for (int i = 0; i < 4; ++i) {
            float v[4]; int nn[4];
            #pragma unroll
            for (int ni = 0; ni < 4; ++ni) {
                int cl = wc * 64 + ni * 16 + col16;
                v[ni] = acc[mi][ni][i] + bgl[cl];
                nn[ni] = n0 + cl;
            }
            float lv = v[0]; int li = nn[0];
            #pragma unroll
            for (int ni = 1; ni < 4; ++ni)
                if (v[ni] > lv) { lv = v[ni]; li = nn[ni]; }
            #pragma unroll
            for (int off = 1; off < 16; off <<= 1) {
                float ov = __shfl_xor(lv, off); int oi = __shfl_xor(li, off);
                if (ov > lv || (ov == lv && oi < li)) { lv = ov; li = oi; }
            }
            float nM = lv;
            float add = 0.f;
            if (nM != -INFINITY) {
                #pragma unroll
                for (int ni = 0; ni < 4; ++ni) add += expf(v[ni] - nM);
                #pragma unroll
                for (int off = 1; off < 16; off <<= 1) add += __shfl_xor(add, off);
            }
            M[mi][i] = nM; S[mi][i] = add;
            AV[mi][i] = lv; AI[mi][i] = li;
            float tv = -INFINITY;
            #pragma unroll
            for (int ni = 0; ni < 4; ++ni)
                if (nn[ni] == tgt[mi][i]) tv = v[ni];
            #pragma unroll
            for (int off = 1; off < 16; off <<= 1)
                tv = fmaxf(tv, __shfl_xor(tv, off));
            TGT[mi][i] = tv;
        }
    // ---- merge wc=1 into wc=0 via LDS, write partials ----
    __syncthreads();
    if (wc == 1 && col16 == 0) {
        #pragma unroll
        for (int mi = 0; mi < 4; ++mi)
            #pragma unroll
            for (int i = 0; i < 4; ++i) {
                int rl = wr * 64 + mi * 16 + rq + i;
                mrg[rl][0] = M[mi][i]; mrg[rl][1] = S[mi][i];
                mrg[rl][2] = AV[mi][i]; mrg[rl][3] = __int_as_float(AI[mi][i]);
                mrg[rl][4] = TGT[mi][i];
            }
    }
    __syncthreads();
    if (wc == 0 && col16 == 0) {
        #pragma unroll
        for (int mi = 0; mi < 4; ++mi)
            #pragma unroll
            for (int i = 0; i < 4; ++i) {
                int rl = wr * 64 + mi * 16 + rq + i;
                float oM = mrg[rl][0], oS = mrg[rl][1], oAV = mrg[rl][2];
                int oAI = __float_as_int(mrg[rl][3]);
                float oT = mrg[rl][4];
                float nM = fmaxf(M[mi][i], oM);
                float s1 = (S[mi][i] > 0.f) ? S[mi][i] * expf(M[mi][i] - nM) : 0.f;
                float s2 = (oS > 0.f) ? oS * expf(oM - nM) : 0.f;
                float av = AV[mi][i]; int ai = AI[mi][i];
                if (oAV > av || (oAV == av && oAI < ai)) { av = oAV; ai = oAI; }
                float* p = pst + ((size_t)chunk * R_ + (m0 + rl)) * 8;
                p[0] = nM; p[1] = s1 + s2; p[2] = av;
                p[3] = __int_as_float(ai); p[4] = fmaxf(TGT[mi][i], oT);
            }
    }
}

// ---------------- final merge: per-row LSE/argmax/loss/pred ----------------
__launch_bounds__(64)
__global__ void k_loss2(const float* __restrict__ pst, const float* __restrict__ logattn,
                        const float* __restrict__ stbuf, float* __restrict__ out)
{
    const int r = blockIdx.x;
    const int lane = threadIdx.x;
    float M = -INFINITY, S = 0.f, AV = -INFINITY, TGT = -INFINITY;
    int AI = 0x7FFFFFFF;
    for (int c = lane; c < NCHUNK; c += 64) {
        const float* p = pst + ((size_t)c * R_ + r) * 8;
        float oM = p[0], oS = p[1], oAV = p[2];
        int oAI = __float_as_int(p[3]);
        float oT = p[4];
        float nM = fmaxf(M, oM);
        float s1 = (S > 0.f) ? S * expf(M - nM) : 0.f;
        float s2 = (oS > 0.f) ? oS * expf(oM - nM) : 0.f;
        M = nM; S = s1 + s2;
        if (oAV > AV || (oAV == AV && oAI < AI)) { AV = oAV; AI = oAI; }
        TGT = fmaxf(TGT, oT);
    }
    for (int off = 32; off; off >>= 1) {
        float oM = __shfl_xor(M, off), oS = __shfl_xor(S, off);
        float oAV = __shfl_xor(AV, off), oT = __shfl_xor(TGT, off);
        int oAI = __shfl_xor(AI, off);
        float nM = fmaxf(M, oM);
        float s1 = (S > 0.f) ? S * expf(M - nM) : 0.f;
        float s2 = (oS > 0.f) ? oS * expf(oM - nM) : 0.f;
        M = nM; S = s1 + s2;
        if (oAV > AV || (oAV == AV && oAI < AI)) { AV = oAV; AI = oAI; }
        TGT = fmaxf(TGT, oT);
    }
    if (lane == 0) {
        float lse = M + logf(S);
        float st = stbuf[r];
        const float* la = logattn + (size_t)r * A_;
        float lamax = la[0]; int aidx = 0;
        for (int a = 1; a < A_; ++a) if (la[a] > lamax) { lamax = la[a]; aidx = a; }
        float e1 = -expm1f(st);
        e1 = fminf(fmaxf(e1, 1e-18f), 1e18f);
        float lm = logf(e1);
        float p1 = st + M - lse;
        float p2 = lm + lamax;
        int pred = (p1 >= p2) ? AI : (NG_ + aidx);
        float loss = -(st + TGT - lse);
        atomicAdd(&out[0], loss);
        int t = r >> 3, b = r & 7;
        out[1 + b * L_ + t] = (float)pred;
    }
}

extern "C" void kernel_launch(void* const* d_in, const int* in_sizes, int n_in,
                              void* d_out, int out_size, void* d_ws, size_t ws_size,
                              hipStream_t stream)
{
    (void)in_sizes; (void)n_in; (void)out_size; (void)ws_size;
    const int*   nt    = (const int*)d_in[0];
    const int*   tt    = (const int*)d_in[1];
    const int*   pt    = (const int*)d_in[2];
    const float* embN  = (const float*)d_in[3];
    const float* embT  = (const float*)d_in[4];
    const float* W_hid = (const float*)d_in[5];
    const float* b_hid = (const float*)d_in[6];
    const float* W_mem = (const float*)d_in[7];
    const float* b_mem = (const float*)d_in[8];
    const float* v_w   = (const float*)d_in[9];
    const float* v_b   = (const float*)d_in[10];
    const float* W_ih  = (const float*)d_in[11];
    const float* W_hh  = (const float*)d_in[12];
    const float* b_ih  = (const float*)d_in[13];
    const float* b_hh  = (const float*)d_in[14];
    const float* W_g   = (const float*)d_in[15];
    const float* b_g   = (const float*)d_in[16];
    const float* W_s   = (const float*)d_in[17];
    const float* b_s   = (const float*)d_in[18];
    float* out = (float*)d_out;

    char* ws = (char*)d_ws;
    size_t o = 0;
    bf16*  WGT  = (bf16*)(ws + o);  o += (size_t)NGP_ * 1536 * 2;   // 31.5 MB, [N][K]
    float* XG   = (float*)(ws + o); o += (size_t)R_ * 2048 * 4;     // 8.4 MB
    bf16*  HSB  = (bf16*)(ws + o);  o += (size_t)R_ * H_ * 2;       // 1 MB
    float* KMQ  = (float*)(ws + o); o += (size_t)R_ * 1024 * 4;     // 4 MB
    bf16*  WKQ  = (bf16*)(ws + o);  o += (size_t)1024 * 512 * 2;    // 1 MB
    float* BKQ  = (float*)(ws + o); o += (size_t)1024 * 4;
    bf16*  XB   = (bf16*)(ws + o);  o += (size_t)R_ * H_ * 2;       // 1 MB
    bf16*  WIHB = (bf16*)(ws + o);  o += (size_t)2048 * 512 * 2;    // 2 MB
    bf16*  GC   = (bf16*)(ws + o);  o += (size_t)R_ * 1536 * 2;     // 3.1 MB
    float* LA   = (float*)(ws + o); o += (size_t)R_ * A_ * 4;
    float* ST   = (float*)(ws + o); o += (size_t)R_ * 4;
    float* PST  = (float*)(ws + o); o += (size_t)NCHUNK * R_ * 8 * 4; // 2.6 MB
    unsigned long long* BFR = (unsigned long long*)(ws + o); o += (size_t)4096 * 8;
    int*   FLG  = (int*)(ws + o);   o += 256;

    k_prep<<<2048, 256, 0, stream>>>(FLG, BKQ, b_mem, b_hid, out,
                                     W_ih, WIHB, nt, tt, embN, embT, XB);
    k_gemm128b<<<dim3(2048 / 128, R_ / 128), 256, 0, stream>>>(XB, WIHB, b_ih, b_hh, XG, 2048, 512);
    k_lstm<<<LSTM_BLOCKS + XTRA, 512, 0, stream>>>(W_hh, XG, HSB, BFR, FLG,
                                                   W_g, WGT, W_mem, W_hid, WKQ);
    k_gemm128b<<<dim3(1024 / 128, R_ / 128), 256, 0, stream>>>(HSB, WKQ, BKQ, nullptr, KMQ, 1024, 512);
    k_attn<<<R_, 256, 0, stream>>>(HSB, KMQ, v_w, v_b, nt, pt, W_s, b_s, GC, LA, ST);
    k_gemm128p<<<dim3(NCHUNK, R_ / 128), 256, 0, stream>>>(GC, WGT, b_g, tt, PST);
    k_loss2<<<R_, 64, 0, stream>>>(PST, LA, ST, out);
}

// Round 14
// 563.047 us; speedup vs baseline: 1.2076x; 1.2076x over previous
//
#include <hip/hip_runtime.h>
#include <hip/hip_bf16.h>
#include <math.h>

#define H_ 512
#define VN_ 1000
#define NG_ 10003    // VT+3
#define NGP_ 10240   // padded N (80 tiles of 128)
#define NCHUNK 80
#define A_ 50
#define B_ 8
#define L_ 128
#define R_ 1024      // L*B

typedef __hip_bfloat16 bf16;
typedef __attribute__((ext_vector_type(8))) short bf16x8;
typedef __attribute__((ext_vector_type(4))) float f32x4;

typedef union { unsigned long long u[2]; bf16x8 v; } frag_u;

__device__ __forceinline__ float fsig(float x) { return 1.0f / (1.0f + __expf(-x)); }
__device__ __forceinline__ float ftanh(float x) { return 1.0f - 2.0f / (1.0f + __expf(2.0f * x)); }

__device__ __forceinline__ short b16(float v) {
    __hip_bfloat16 h = __float2bfloat16(v);
    return *(short*)&h;
}

__device__ __forceinline__ unsigned long long ald(const unsigned long long* p) {
    return __hip_atomic_load(p, __ATOMIC_RELAXED, __HIP_MEMORY_SCOPE_AGENT);
}
__device__ __forceinline__ int aldi(const int* p) {
    return __hip_atomic_load(p, __ATOMIC_RELAXED, __HIP_MEMORY_SCOPE_AGENT);
}
__device__ __forceinline__ void ast32(unsigned int* p, unsigned int v) {
    __hip_atomic_store(p, v, __ATOMIC_RELAXED, __HIP_MEMORY_SCOPE_AGENT);
}
__device__ __forceinline__ void asti(int* p, int v) {
    __hip_atomic_store(p, v, __ATOMIC_RELAXED, __HIP_MEMORY_SCOPE_AGENT);
}

// ---------------- prep: flags + bias concat + out init + W_ih->bf16 + embedding ----------------
__global__ void k_prep(int* flags, float* bkq,
                       const float* __restrict__ bmem, const float* __restrict__ bhid,
                       float* out,
                       const float* __restrict__ Wih, bf16* __restrict__ wihb,
                       const int* __restrict__ nt, const int* __restrict__ tt,
                       const float* __restrict__ embN, const float* __restrict__ embT,
                       bf16* __restrict__ X)
{
    const int i = blockIdx.x * 256 + threadIdx.x;   // 0 .. 524287
    const int total = gridDim.x * 256;
    if (i < 32)
        __hip_atomic_store(&flags[i], 0, __ATOMIC_RELAXED, __HIP_MEMORY_SCOPE_AGENT);
    if (i < 1024) bkq[i] = (i < 512) ? bmem[i] : bhid[i - 512];
    if (i == 0) out[0] = 0.f;
    for (int j = i; j < 2048 * 512; j += total)
        wihb[j] = __float2bfloat16(Wih[j]);
    {
        int r = i >> 9, k = i & 511;
        int t = r >> 3, b = r & 7;
        float v;
        if (k < 256) {
            int id = (t == 0) ? 0 : nt[b * L_ + t - 1];
            v = embN[id * 256 + k];
        } else {
            int id = (t == 0) ? 0 : tt[b * L_ + t - 1];
            v = embT[id * 256 + (k - 256)];
        }
        X[i] = __float2bfloat16(v);
    }
}

// ---------------- persistent LSTM (blocks 0-15) + W_g transpose / WKQ convert (blocks 16+) ----------------
#define LSTM_BLOCKS 16
#define XTRA 240

#define DECLW(i) bf16x8 Wa##i, Wb##i;
#define LOADW(i) { \
    float4 a0 = *(const float4*)(wr0 + (i)*32); \
    float4 a1 = *(const float4*)(wr0 + (i)*32 + 4); \
    float4 c0 = *(const float4*)(wr1 + (i)*32); \
    float4 c1 = *(const float4*)(wr1 + (i)*32 + 4); \
    Wa##i[0]=b16(a0.x); Wa##i[1]=b16(a0.y); Wa##i[2]=b16(a0.z); Wa##i[3]=b16(a0.w); \
    Wa##i[4]=b16(a1.x); Wa##i[5]=b16(a1.y); Wa##i[6]=b16(a1.z); Wa##i[7]=b16(a1.w); \
    Wb##i[0]=b16(c0.x); Wb##i[1]=b16(c0.y); Wb##i[2]=b16(c0.z); Wb##i[3]=b16(c0.w); \
    Wb##i[4]=b16(c1.x); Wb##i[5]=b16(c1.y); Wb##i[6]=b16(c1.z); Wb##i[7]=b16(c1.w); }
#define LDF(i) frag_u fu##i; fu##i.u[0] = ald(src + (i)*128); fu##i.u[1] = ald(src + (i)*128 + 1);
#define MM(i) \
    acc0 = __builtin_amdgcn_mfma_f32_16x16x32_bf16(Wa##i, fu##i.v, acc0, 0, 0, 0); \
    acc1 = __builtin_amdgcn_mfma_f32_16x16x32_bf16(Wb##i, fu##i.v, acc1, 0, 0, 0);

__launch_bounds__(256, 1)
__global__ void k_lstm(const float* __restrict__ Whh, const float* __restrict__ xg,
                       bf16* __restrict__ hsb,
                       unsigned long long* __restrict__ bfr, int* __restrict__ flags,
                       const float* __restrict__ Wg, bf16* __restrict__ WT,
                       const float* __restrict__ Wmem, const float* __restrict__ Whid,
                       bf16* __restrict__ wkq)
{
    __shared__ float gl[4][32][9];   // [gate][unit][batch] (+pad)  -- LSTM path
    __shared__ short S[64][65];      // transpose staging           -- extra-block path
    const int tid  = threadIdx.x;
    const int x    = blockIdx.x;

    if (x >= LSTM_BLOCKS) {
        // ---- side work riding under the latency-bound LSTM (no polling!) ----
        for (int i = (x - LSTM_BLOCKS) * 256 + tid; i < 2 * 512 * 512; i += XTRA * 256) {
            float v = (i < 512 * 512) ? Wmem[i] : Whid[i - 512 * 512];
            wkq[i] = __float2bfloat16(v);
        }
        const int c = tid & 63;
        const int r0 = (tid >> 6) * 16;
        const int n_l = tid >> 2;
        const int kq = (tid & 3) * 16;
        for (int tile = x - LSTM_BLOCKS; tile < 160 * 24; tile += XTRA) {
            int n0 = (tile % 160) * 64, k0 = (tile / 160) * 64;
            __syncthreads();
            #pragma unroll
            for (int i = 0; i < 16; ++i) {
                int k = r0 + i;
                int n = n0 + c;
                float v = (n < NG_) ? Wg[(size_t)(k0 + k) * NG_ + n] : 0.f;
                S[c][k] = b16(v);
            }
            __syncthreads();
            bf16* dst = WT + (size_t)(n0 + n_l) * 1536 + k0 + kq;
            #pragma unroll
            for (int j = 0; j < 2; ++j) {
                bf16x8 v;
                #pragma unroll
                for (int e = 0; e < 8; ++e) v[e] = S[n_l][kq + j * 8 + e];
                *(bf16x8*)(dst + j * 8) = v;
            }
        }
        return;
    }

    const int lane = tid & 63;
    const int w    = tid >> 6;       // wave = gate index 0..3 (i,f,g,o)
    const int m_l  = lane & 15;      // MFMA row within tile
    const int kg   = lane >> 4;      // k-group
    const int n    = lane & 15;      // MFMA col = batch (valid < 8)
    unsigned int* bfr32 = (unsigned int*)bfr;

    // ---- Whh rows -> VGPR/AGPR bf16 A-fragments (once) ----
    const float* wr0 = Whh + (size_t)(w * 512 + x * 32 + m_l) * 512 + kg * 8;
    const float* wr1 = wr0 + (size_t)16 * 512;
    DECLW(0)  DECLW(1)  DECLW(2)  DECLW(3)  DECLW(4)  DECLW(5)  DECLW(6)  DECLW(7)
    DECLW(8)  DECLW(9)  DECLW(10) DECLW(11) DECLW(12) DECLW(13) DECLW(14) DECLW(15)
    LOADW(0)  LOADW(1)  LOADW(2)  LOADW(3)  LOADW(4)  LOADW(5)  LOADW(6)  LOADW(7)
    LOADW(8)  LOADW(9)  LOADW(10) LOADW(11) LOADW(12) LOADW(13) LOADW(14) LOADW(15)
    asm volatile("" : "+v"(Wa0), "+v"(Wb0), "+v"(Wa1), "+v"(Wb1), "+v"(Wa2), "+v"(Wb2),
                      "+v"(Wa3), "+v"(Wb3), "+v"(Wa4), "+v"(Wb4), "+v"(Wa5), "+v"(Wb5),
                      "+v"(Wa6), "+v"(Wb6), "+v"(Wa7), "+v"(Wb7));
    asm volatile("" : "+v"(Wa8), "+v"(Wb8), "+v"(Wa9), "+v"(Wb9), "+v"(Wa10), "+v"(Wb10),
                      "+v"(Wa11), "+v"(Wb11), "+v"(Wa12), "+v"(Wb12), "+v"(Wa13), "+v"(Wb13),
                      "+v"(Wa14), "+v"(Wb14), "+v"(Wa15), "+v"(Wb15));

    const int u_l = tid >> 3;        // pointwise: unit 0..31
    const int b   = tid & 7;         //            batch 0..7
    float creg = 0.f;
    int fearly = 0;                  // pre-sampled flag value (monotone -> safe)

    for (int t = 0; t < L_; ++t) {
        const float* xr = xg + ((size_t)t * B_ + b) * 2048 + x * 32 + u_l;
        float xi = xr[0], xf = xr[512], xgg = xr[1024], xo = xr[1536];

        f32x4 acc0 = {0.f, 0.f, 0.f, 0.f};
        f32x4 acc1 = {0.f, 0.f, 0.f, 0.f};
        if (t > 0) {
            if (!__all(fearly >= t)) {
                for (;;) {
                    int v = (lane < LSTM_BLOCKS) ? aldi(&flags[lane]) : t;
                    if (__all(v >= t)) break;
                    __builtin_amdgcn_s_sleep(1);
                }
            }
            const unsigned long long* src =
                bfr + (size_t)((t + 1) & 1) * 2048 + lane * 2;
            LDF(0)  LDF(1)  LDF(2)  LDF(3)  LDF(4)  LDF(5)  LDF(6)  LDF(7)
            LDF(8)  LDF(9)  LDF(10) LDF(11) LDF(12) LDF(13) LDF(14) LDF(15)
            __builtin_amdgcn_sched_barrier(0);
            MM(0)  MM(1)  MM(2)  MM(3)  MM(4)  MM(5)  MM(6)  MM(7)
            MM(8)  MM(9)  MM(10) MM(11) MM(12) MM(13) MM(14) MM(15)
        }
        if (n < 8) {
            #pragma unroll
            for (int i = 0; i < 4; ++i) {
                gl[w][kg * 4 + i][n]      = acc0[i];
                gl[w][16 + kg * 4 + i][n] = acc1[i];
            }
        }
        __syncthreads();
        float gi = gl[0][u_l][b] + xi;
        float gf = gl[1][u_l][b] + xf;
        float gg = gl[2][u_l][b] + xgg;
        float go = gl[3][u_l][b] + xo;
        float iv = fsig(gi), fv = fsig(gf), gv = ftanh(gg), ov = fsig(go);
        creg = fv * creg + iv * gv;
        float h = ov * ftanh(creg);
        float h2 = __shfl_xor(h, 8);   // partner unit u_l^1 (same wave)
        unsigned pay = 0;
        if ((u_l & 1) == 0) {
            pay = (unsigned)(unsigned short)b16(h)
                | ((unsigned)(unsigned short)b16(h2) << 16);
            int q = u_l >> 3, p = (u_l & 7) >> 1;
            ast32(bfr32 + (size_t)(t & 1) * 4096 + x * 256 + (b + 16 * q) * 4 + p, pay);
        }
        fearly = (lane < LSTM_BLOCKS && lane != x) ? aldi(&flags[lane]) : 0x7FFFFFFF;
        asm volatile("s_waitcnt vmcnt(0)" ::: "memory");  // frag stores (and sample) done
        __syncthreads();
        if (tid == 0)
            asti(&flags[x], t + 1);
        if ((u_l & 1) == 0)
            *(unsigned int*)(hsb + (size_t)(t * B_ + b) * 512 + x * 32 + u_l) = pay;
    }
}

// ---------------- attention + context + gcat(bf16) + st, one block per (t,b) ----------------
__launch_bounds__(256)
__global__ void k_attn(const bf16* __restrict__ hsb, const float* __restrict__ kmq,
                       const float* __restrict__ vw,
                       const float* __restrict__ vb, const int* __restrict__ nt,
                       const int* __restrict__ pt, const float* __restrict__ Wsv,
                       const float* __restrict__ bs, bf16* __restrict__ gcat,
                       float* __restrict__ logattn, float* __restrict__ stbuf)
{
    const int r = blockIdx.x;
    const int t = r >> 3, b = r & 7;
    const int tid = threadIdx.x;
    const int lane = tid & 63, wave = tid >> 6;
    int s = t - A_; if (s < 0) s = 0;
    __shared__ float qv[512];
    __shared__ float vwl[512];
    __shared__ float sc[A_];
    __shared__ float attn[A_];
    __shared__ float red[4];
    for (int i = tid; i < 512; i += 256) {
        qv[i] = kmq[(size_t)r * 1024 + 512 + i];   // QB half
        vwl[i] = vw[i];
    }
    __syncthreads();
    for (int a = wave; a < A_; a += 4) {
        int pos = s + a;
        float v = -1e20f;
        bool masked = (pos >= t) || (nt[b * L_ + pos] == VN_ - 1);
        if (!masked) {
            const float* kr = kmq + (size_t)(pos * B_ + b) * 1024;   // KM half
            float p = 0.f;
            for (int k = lane; k < 512; k += 64)
                p += vwl[k] * ftanh(qv[k] + kr[k]);
            for (int off = 32; off; off >>= 1) p += __shfl_down(p, off);
            v = p + vb[0];
        }
        if (lane == 0) sc[a] = v;
    }
    __syncthreads();
    if (tid < 64) {   // masked softmax over 50 (exact -1e20 semantics; all-masked -> uniform)
        float v = (tid < A_) ? sc[tid] : -INFINITY;
        float m = v;
        for (int off = 32; off; off >>= 1) m = fmaxf(m, __shfl_xor(m, off));
        float e = (tid < A_) ? expf(v - m) : 0.f;
        float d = e;
        for (int off = 32; off; off >>= 1) d += __shfl_xor(d, off);
        if (tid < A_) {
            attn[tid] = e / d;
            logattn[(size_t)r * A_ + tid] = (v - m) - logf(d);
        }
    }
    __syncthreads();
    const int k0 = tid * 2;
    float c0 = 0.f, c1 = 0.f;
    for (int a = 0; a < A_; ++a) {
        int pos = s + a;
        if (pos >= t) break;   // hs rows >= t were zeros at step t (ref semantics)
        float w = attn[a];
        unsigned u = *(const unsigned*)((const unsigned short*)hsb + (size_t)(pos * B_ + b) * 512 + k0);
        c0 += w * __uint_as_float(u << 16);
        c1 += w * __uint_as_float(u & 0xffff0000u);
    }
    unsigned ucur = *(const unsigned*)((const unsigned short*)hsb + (size_t)(t * B_ + b) * 512 + k0);
    int par = (t == 0) ? 0 : pt[b * L_ + t - 1];
    unsigned upar = 0;
    if (par < t)
        upar = *(const unsigned*)((const unsigned short*)hsb + (size_t)(par * B_ + b) * 512 + k0);
    float hx = __uint_as_float(ucur << 16), hy = __uint_as_float(ucur & 0xffff0000u);
    bf16* g = gcat + (size_t)r * 1536;
    g[k0]     = __float2bfloat16(c0);
    g[k0 + 1] = __float2bfloat16(c1);
    *(unsigned*)(g + 512 + k0)  = ucur;
    *(unsigned*)(g + 1024 + k0) = upar;
    float part = c0 * Wsv[k0] + c1 * Wsv[k0 + 1]
               + hx * Wsv[512 + k0] + hy * Wsv[512 + k0 + 1];
    for (int off = 32; off; off >>= 1) part += __shfl_down(part, off);
    if (lane == 0) red[wave] = part;
    __syncthreads();
    if (tid == 0) {
        float z = red[0] + red[1] + red[2] + red[3] + bs[0];
        stbuf[r] = -log1pf(expf(-z));   // log_sigmoid(z)
    }
}

// ---------------- 128x128 MFMA GEMM with global_load_lds + bias: XG / KMQ ----------------
__launch_bounds__(256, 2)
__global__ void k_gemm128b(const bf16* __restrict__ Ag, const bf16* __restrict__ Bg,
                           const float* __restrict__ b1, const float* __restrict__ b2,
                           float* __restrict__ C, int N, int K)
{
    __shared__ short As[128 * 32];
    __shared__ short Bs[128 * 32];
    const int tid = threadIdx.x;
    const int lane = tid & 63, wave = tid >> 6;
    const int wr = wave >> 1, wc = wave & 1;
    const int m0 = blockIdx.y * 128, n0 = blockIdx.x * 128;
    f32x4 acc[4][4] = {};
    for (int k0 = 0; k0 < K; k0 += 32) {
        __syncthreads();
        #pragma unroll
        for (int h = 0; h < 2; ++h) {
            int o = tid + h * 256;
            int row = o >> 2;
            int kc = (o & 3) ^ (row & 3);
            const bf16* ga = Ag + (size_t)(m0 + row) * K + k0 + kc * 8;
            const bf16* gb = Bg + (size_t)(n0 + row) * K + k0 + kc * 8;
            unsigned ldso = h * 4096 + wave * 1024;
            __builtin_amdgcn_global_load_lds(
                (const __attribute__((address_space(1))) void*)ga,
                (__attribute__((address_space(3))) void*)((char*)As + ldso), 16, 0, 0);
            __builtin_amdgcn_global_load_lds(
                (const __attribute__((address_space(1))) void*)gb,
                (__attribute__((address_space(3))) void*)((char*)Bs + ldso), 16, 0, 0);
        }
        asm volatile("s_waitcnt vmcnt(0)" ::: "memory");
        __syncthreads();
        bf16x8 af[4], bf[4];
        #pragma unroll
        for (int mi = 0; mi < 4; ++mi) {
            int ra = wr * 64 + mi * 16 + (lane & 15);
            af[mi] = *(const bf16x8*)&As[ra * 32 + (((lane >> 4) ^ (ra & 3)) * 8)];
        }
        #pragma unroll
        for (int ni = 0; ni < 4; ++ni) {
            int rb = wc * 64 + ni * 16 + (lane & 15);
            bf[ni] = *(const bf16x8*)&Bs[rb * 32 + (((lane >> 4) ^ (rb & 3)) * 8)];
        }
        #pragma unroll
        for (int mi = 0; mi < 4; ++mi)
            #pragma unroll
            for (int ni = 0; ni < 4; ++ni)
                acc[mi][ni] = __builtin_amdgcn_mfma_f32_16x16x32_bf16(af[mi], bf[ni], acc[mi][ni], 0, 0, 0);
    }
    const int col = lane & 15, rq = (lane >> 4) * 4;
    #pragma unroll
    for (int mi = 0; mi < 4; ++mi)
        #pragma unroll
        for (int ni = 0; ni < 4; ++ni) {
            int nn = n0 + wc * 64 + ni * 16 + col;
            float bias = (b1 ? b1[nn] : 0.f) + (b2 ? b2[nn] : 0.f);
            #pragma unroll
            for (int i = 0; i < 4; ++i)
                C[(size_t)(m0 + wr * 64 + mi * 16 + rq + i) * N + nn] = acc[mi][ni][i] + bias;
        }
}

// ---------------- fused logits GEMM (128x128/block) + online LSE/argmax partials ----------------
__launch_bounds__(256, 2)
__global__ void k_gemm128p(const bf16* __restrict__ Ag, const bf16* __restrict__ Bg,
                           const float* __restrict__ bg, const int* __restrict__ tt,
                           float* __restrict__ pst)
{
    __shared__ short As[128 * 32];
    __shared__ short Bs[128 * 32];
    __shared__ float bgl[128];
    __shared__ float mrg[128][6];
    const int tid = threadIdx.x;
    const int lane = tid & 63, wave = tid >> 6;
    const int wr = wave >> 1, wc = wave & 1;
    const int col16 = lane & 15, rq = (lane >> 4) * 4;
    const int chunk = blockIdx.x;
    const int m0 = blockIdx.y * 128;
    const int n0 = chunk * 128;
    const int K = 1536;

    if (tid < 128) bgl[tid] = (n0 + tid < NG_) ? bg[n0 + tid] : -INFINITY;

    float M[4][4], S[4][4], AV[4][4], TGT[4][4]; int AI[4][4]; int tgt[4][4];
    #pragma unroll
    for (int mi = 0; mi < 4; ++mi)
        #pragma unroll
        for (int i = 0; i < 4; ++i) {
            M[mi][i] = -INFINITY; S[mi][i] = 0.f; AV[mi][i] = -INFINITY;
            TGT[mi][i] = -INFINITY; AI[mi][i] = 0x7FFFFFFF;
            int row = m0 + wr * 64 + mi * 16 + rq + i;
            tgt[mi][i] = tt[(row & 7) * L_ + (row >> 3)];
        }

    f32x4 acc[4][4] = {};
    for (int k0 = 0; k0 < K; k0 += 32) {
        __syncthreads();
        #pragma unroll
        for (int h = 0; h < 2; ++h) {
            int o = tid + h * 256;
            int row = o >> 2;
            int kc = (o & 3) ^ (row & 3);
            const bf16* ga = Ag + (size_t)(m0 + row) * K + k0 + kc * 8;
            const bf16* gb = Bg + (size_t)(n0 + row) * K + k0 + kc * 8;
            unsigned ldso = h * 4096 + wave * 1024;
            __builtin_amdgcn_global_load_lds(
                (const __attribute__((address_space(1))) void*)ga,
                (__attribute__((address_space(3))) void*)((char*)As + ldso), 16, 0, 0);
            __builtin_amdgcn_global_load_lds(
                (const __attribute__((address_space(1))) void*)gb,
                (__attribute__((address_space(3))) void*)((char*)Bs + ldso), 16, 0, 0);
        }
        asm volatile("s_waitcnt vmcnt(0)" ::: "memory");
        __syncthreads();
        bf16x8 af[4], bf[4];
        #pragma unroll
        for (int mi = 0; mi < 4; ++mi) {
            int ra = wr * 64 + mi * 16 + col16;
            af[mi] = *(const bf16x8*)&As[ra * 32 + (((lane >> 4) ^ (ra & 3)) * 8)];
        }
        #pragma unroll
        for (int ni = 0; ni < 4; ++ni) {
            int rb = wc * 64 + ni * 16 + col16;
            bf[ni] = *(const bf16x8*)&Bs[rb * 32 + (((lane >> 4) ^ (rb & 3)) * 8)];
        }
        #pragma unroll
        for (int mi = 0; mi < 4; ++mi)
            #pragma unroll
            for (int ni = 0; ni < 4; ++ni)
                acc[mi][ni] = __builtin_amdgcn_mfma_f32_16x16x32_bf16(af[mi], bf[ni], acc[mi][ni], 0, 0, 0);
    }
    // ---- per-row stats over this 128-col tile ----
    #pragma unroll
    for (int mi = 0; mi < 4; ++mi)
        #pragma unroll
        for (int i = 0; i < 4; ++i) {
            float v[4]; int nn[4];
            #pragma unroll
            for (int ni = 0; ni < 4; ++ni) {
                int cl = wc * 64 + ni * 16 + col16;
                v[ni] = acc[mi][ni][i] + bgl[cl];
                nn[ni] = n0 + cl;
            }
            float lv = v[0]; int li = nn[0];
            #pragma unroll
            for (int ni = 1; ni < 4; ++ni)
                if (v[ni] > lv) { lv = v[ni]; li = nn[ni]; }
            #pragma unroll
            for (int off = 1; off < 16; off <<= 1) {
                float ov = __shfl_xor(lv, off); int oi = __shfl_xor(li, off);
                if (ov > lv || (ov == lv && oi < li)) { lv = ov; li = oi; }
            }
            float nM = lv;
            float add = 0.f;
            if (nM != -INFINITY) {
                #pragma unroll
                for (int ni = 0; ni < 4; ++ni) add += expf(v[ni] - nM);
                #pragma unroll
                for (int off = 1; off < 16; off <<= 1) add += __shfl_xor(add, off);
            }
            M[mi][i] = nM; S[mi][i] = add;
            AV[mi][i] = lv; AI[mi][i] = li;
            float tv = -INFINITY;
            #pragma unroll
            for (int ni = 0; ni < 4; ++ni)
                if (nn[ni] == tgt[mi][i]) tv = v[ni];
            #pragma unroll
            for (int off = 1; off < 16; off <<= 1)
                tv = fmaxf(tv, __shfl_xor(tv, off));
            TGT[mi][i] = tv;
        }
    // ---- merge wc=1 into wc=0 via LDS, write partials ----
    __syncthreads();
    if (wc == 1 && col16 == 0) {
        #pragma unroll
        for (int mi = 0; mi < 4; ++mi)
            #pragma unroll
            for (int i = 0; i < 4; ++i) {
                int rl = wr * 64 + mi * 16 + rq + i;
                mrg[rl][0] = M[mi][i]; mrg[rl][1] = S[mi][i];
                mrg[rl][2] = AV[mi][i]; mrg[rl][3] = __int_as_float(AI[mi][i]);
                mrg[rl][4] = TGT[mi][i];
            }
    }
    __syncthreads();
    if (wc == 0 && col16 == 0) {
        #pragma unroll
        for (int mi = 0; mi < 4; ++mi)
            #pragma unroll
            for (int i = 0; i < 4; ++i) {
                int rl = wr * 64 + mi * 16 + rq + i;
                float oM = mrg[rl][0], oS = mrg[rl][1], oAV = mrg[rl][2];
                int oAI = __float_as_int(mrg[rl][3]);
                float oT = mrg[rl][4];
                float nM = fmaxf(M[mi][i], oM);
                float s1 = (S[mi][i] > 0.f) ? S[mi][i] * expf(M[mi][i] - nM) : 0.f;
                float s2 = (oS > 0.f) ? oS * expf(oM - nM) : 0.f;
                float av = AV[mi][i]; int ai = AI[mi][i];
                if (oAV > av || (oAV == av && oAI < ai)) { av = oAV; ai = oAI; }
                float* p = pst + ((size_t)chunk * R_ + (m0 + rl)) * 8;
                p[0] = nM; p[1] = s1 + s2; p[2] = av;
                p[3] = __int_as_float(ai); p[4] = fmaxf(TGT[mi][i], oT);
            }
    }
}

// ---------------- final merge: per-row LSE/argmax/loss/pred ----------------
__launch_bounds__(64)
__global__ void k_loss2(const float* __restrict__ pst, const float* __restrict__ logattn,
                        const float* __restrict__ stbuf, float* __restrict__ out)
{
    const int r = blockIdx.x;
    const int lane = threadIdx.x;
    float M = -INFINITY, S = 0.f, AV = -INFINITY, TGT = -INFINITY;
    int AI = 0x7FFFFFFF;
    for (int c = lane; c < NCHUNK; c += 64) {
        const float* p = pst + ((size_t)c * R_ + r) * 8;
        float oM = p[0], oS = p[1], oAV = p[2];
        int oAI = __float_as_int(p[3]);
        float oT = p[4];
        float nM = fmaxf(M, oM);
        float s1 = (S > 0.f) ? S * expf(M - nM) : 0.f;
        float s2 = (oS > 0.f) ? oS * expf(oM - nM) : 0.f;
        M = nM; S = s1 + s2;
        if (oAV > AV || (oAV == AV && oAI < AI)) { AV = oAV; AI = oAI; }
        TGT = fmaxf(TGT, oT);
    }
    for (int off = 32; off; off >>= 1) {
        float oM = __shfl_xor(M, off), oS = __shfl_xor(S, off);
        float oAV = __shfl_xor(AV, off), oT = __shfl_xor(TGT, off);
        int oAI = __shfl_xor(AI, off);
        float nM = fmaxf(M, oM);
        float s1 = (S > 0.f) ? S * expf(M - nM) : 0.f;
        float s2 = (oS > 0.f) ? oS * expf(oM - nM) : 0.f;
        M = nM; S = s1 + s2;
        if (oAV > AV || (oAV == AV && oAI < AI)) { AV = oAV; AI = oAI; }
        TGT = fmaxf(TGT, oT);
    }
    if (lane == 0) {
        float lse = M + logf(S);
        float st = stbuf[r];
        const float* la = logattn + (size_t)r * A_;
        float lamax = la[0]; int aidx = 0;
        for (int a = 1; a < A_; ++a) if (la[a] > lamax) { lamax = la[a]; aidx = a; }
        float e1 = -expm1f(st);
        e1 = fminf(fmaxf(e1, 1e-18f), 1e18f);
        float lm = logf(e1);
        float p1 = st + M - lse;
        float p2 = lm + lamax;
        int pred = (p1 >= p2) ? AI : (NG_ + aidx);
        float loss = -(st + TGT - lse);
        atomicAdd(&out[0], loss);
        int t = r >> 3, b = r & 7;
        out[1 + b * L_ + t] = (float)pred;
    }
}

extern "C" void kernel_launch(void* const* d_in, const int* in_sizes, int n_in,
                              void* d_out, int out_size, void* d_ws, size_t ws_size,
                              hipStream_t stream)
{
    (void)in_sizes; (void)n_in; (void)out_size; (void)ws_size;
    const int*   nt    = (const int*)d_in[0];
    const int*   tt    = (const int*)d_in[1];
    const int*   pt    = (const int*)d_in[2];
    const float* embN  = (const float*)d_in[3];
    const float* embT  = (const float*)d_in[4];
    const float* W_hid = (const float*)d_in[5];
    const float* b_hid = (const float*)d_in[6];
    const float* W_mem = (const float*)d_in[7];
    const float* b_mem = (const float*)d_in[8];
    const float* v_w   = (const float*)d_in[9];
    const float* v_b   = (const float*)d_in[10];
    const float* W_ih  = (const float*)d_in[11];
    const float* W_hh  = (const float*)d_in[12];
    const float* b_ih  = (const float*)d_in[13];
    const float* b_hh  = (const float*)d_in[14];
    const float* W_g   = (const float*)d_in[15];
    const float* b_g   = (const float*)d_in[16];
    const float* W_s   = (const float*)d_in[17];
    const float* b_s   = (const float*)d_in[18];
    float* out = (float*)d_out;

    char* ws = (char*)d_ws;
    size_t o = 0;
    bf16*  WGT  = (bf16*)(ws + o);  o += (size_t)NGP_ * 1536 * 2;   // 31.5 MB, [N][K]
    float* XG   = (float*)(ws + o); o += (size_t)R_ * 2048 * 4;     // 8.4 MB
    bf16*  HSB  = (bf16*)(ws + o);  o += (size_t)R_ * H_ * 2;       // 1 MB
    float* KMQ  = (float*)(ws + o); o += (size_t)R_ * 1024 * 4;     // 4 MB
    bf16*  WKQ  = (bf16*)(ws + o);  o += (size_t)1024 * 512 * 2;    // 1 MB
    float* BKQ  = (float*)(ws + o); o += (size_t)1024 * 4;
    bf16*  XB   = (bf16*)(ws + o);  o += (size_t)R_ * H_ * 2;       // 1 MB
    bf16*  WIHB = (bf16*)(ws + o);  o += (size_t)2048 * 512 * 2;    // 2 MB
    bf16*  GC   = (bf16*)(ws + o);  o += (size_t)R_ * 1536 * 2;     // 3.1 MB
    float* LA   = (float*)(ws + o); o += (size_t)R_ * A_ * 4;
    float* ST   = (float*)(ws + o); o += (size_t)R_ * 4;
    float* PST  = (float*)(ws + o); o += (size_t)NCHUNK * R_ * 8 * 4; // 2.6 MB
    unsigned long long* BFR = (unsigned long long*)(ws + o); o += (size_t)4096 * 8;
    int*   FLG  = (int*)(ws + o);   o += 256;

    k_prep<<<2048, 256, 0, stream>>>(FLG, BKQ, b_mem, b_hid, out,
                                     W_ih, WIHB, nt, tt, embN, embT, XB);
    k_gemm128b<<<dim3(2048 / 128, R_ / 128), 256, 0, stream>>>(XB, WIHB, b_ih, b_hh, XG, 2048, 512);
    k_lstm<<<LSTM_BLOCKS + XTRA, 256, 0, stream>>>(W_hh, XG, HSB, BFR, FLG,
                                                   W_g, WGT, W_mem, W_hid, WKQ);
    k_gemm128b<<<dim3(1024 / 128, R_ / 128), 256, 0, stream>>>(HSB, WKQ, BKQ, nullptr, KMQ, 1024, 512);
    k_attn<<<R_, 256, 0, stream>>>(HSB, KMQ, v_w, v_b, nt, pt, W_s, b_s, GC, LA, ST);
    k_gemm128p<<<dim3(NCHUNK, R_ / 128), 256, 0, stream>>>(GC, WGT, b_g, tt, PST);
    k_loss2<<<R_, 64, 0, stream>>>(PST, LA, ST, out);
}